// Round 4
// baseline (750.369 us; speedup 1.0000x reference)
//
#include <hip/hip_runtime.h>
#include <math.h>

#define GN  4
#define MCN 100
#define BN  512
#define INN 456
#define HN  400
#define ON  10

// softplus(s)^2, numerically stable
__device__ __forceinline__ float sp2f(float s) {
    float l = log1pf(__expf(-fabsf(s)));
    float r = fmaxf(s, 0.0f) + l;
    return r * r;
}

// ---------------- kernel: zero the output (atomicAdd target) ----------------
__global__ __launch_bounds__(256) void k_zero(float* __restrict__ out) {
    int i = blockIdx.x * 256 + threadIdx.x;
    if (i < BN * GN * ON) out[i] = 0.0f;
}

// ---------------- kernel 0a: x -> xT, x^2 -> xxT (tiled transpose) ----------------
__global__ __launch_bounds__(256) void k_transpose(
    const float* __restrict__ x, float* __restrict__ xT, float* __restrict__ xxT) {
    __shared__ float tile[64][65];
    int it = blockIdx.x;           // i tile (8 tiles, tail: 456 = 7*64 + 8)
    int bt = blockIdx.y;           // b tile (8 tiles of 64)
    int tx = threadIdx.x & 63;
    int ty = threadIdx.x >> 6;     // 0..3
    int i_in = it * 64 + tx;
    #pragma unroll
    for (int r = 0; r < 16; ++r) {
        int row = r * 4 + ty;
        int b = bt * 64 + row;
        tile[row][tx] = (i_in < INN) ? x[b * INN + i_in] : 0.0f;
    }
    __syncthreads();
    #pragma unroll
    for (int r = 0; r < 16; ++r) {
        int row = r * 4 + ty;
        int i = it * 64 + row;
        if (i < INN) {
            float v = tile[tx][row];           // stride 65 -> conflict-free
            xT[i * BN + bt * 64 + tx]  = v;
            xxT[i * BN + bt * 64 + tx] = v * v;
        }
    }
}

// ---------------- kernel 0b: sp1 = softplus(sigma1)^2 ----------------
__global__ __launch_bounds__(256) void k_sp1(
    const float* __restrict__ sigma1, float* __restrict__ sp1) {
    int idx = blockIdx.x * 256 + threadIdx.x;
    const int n4 = GN * INN * HN / 4;   // 182400
    if (idx < n4) {
        float4 s = ((const float4*)sigma1)[idx];
        float4 o;
        o.x = sp2f(s.x); o.y = sp2f(s.y); o.z = sp2f(s.z); o.w = sp2f(s.w);
        ((float4*)sp1)[idx] = o;
    }
}

// ---------------- kernel 1: A = x@mu1, S = sqrt((x*x)@sp1) ----------------
// lane = h (coalesced mu1/sp1 dword loads). 4 b's/thread via same-address
// per-lane float4 loads (L1 broadcast, vmcnt-pipelined).
__global__ __launch_bounds__(256, 4) void k_layer1(
    const float* __restrict__ xT, const float* __restrict__ xxT,
    const float* __restrict__ mu1, const float* __restrict__ sp1,
    float* __restrict__ A, float* __restrict__ S) {
    int bt = blockIdx.x;            // 0..31
    int ht = blockIdx.y;            // 0..6
    int g  = blockIdx.z;            // 0..3
    int lane = threadIdx.x & 63;
    int wv   = threadIdx.x >> 6;    // 0..3
    int h = ht * 64 + lane;
    bool hv = h < HN;
    int hc = hv ? h : (HN - 1);     // clamp so masked lanes stay in-bounds
    int b0 = bt * 16 + wv * 4;      // 16B-aligned float4 index
    const float* mp = mu1 + (size_t)g * INN * HN + hc;
    const float* pp = sp1 + (size_t)g * INN * HN + hc;
    float accA[4] = {0.f, 0.f, 0.f, 0.f};
    float accD[4] = {0.f, 0.f, 0.f, 0.f};
    #pragma unroll 8
    for (int k = 0; k < INN; ++k) {       // 456 = 57*8
        float a = mp[(size_t)k * HN];
        float p = pp[(size_t)k * HN];
        float4 xv  = *(const float4*)(xT  + k * BN + b0);
        float4 xxv = *(const float4*)(xxT + k * BN + b0);
        accA[0] = fmaf(a, xv.x,  accA[0]);
        accA[1] = fmaf(a, xv.y,  accA[1]);
        accA[2] = fmaf(a, xv.z,  accA[2]);
        accA[3] = fmaf(a, xv.w,  accA[3]);
        accD[0] = fmaf(p, xxv.x, accD[0]);
        accD[1] = fmaf(p, xxv.y, accD[1]);
        accD[2] = fmaf(p, xxv.z, accD[2]);
        accD[3] = fmaf(p, xxv.w, accD[3]);
    }
    if (hv) {
        #pragma unroll
        for (int j = 0; j < 4; ++j) {
            size_t o = ((size_t)g * BN + (b0 + j)) * HN + h;
            A[o] = accA[j];
            S[o] = sqrtf(accD[j]);
        }
    }
}

// ---------------- kernel 2: layer 2 + softmax + MC mean ----------------
// block = (b, g, mc-chunk-of-50). 400 threads = 25 rg x 16 kc, TM=2:
// m = mb + rg + 25*i -- covers 100 MC rows EXACTLY (no clamp waste, no
// duplicate loads). 40 accumulators/thread (fits VGPRs under (400,4)).
// hval computed once per (m,k), feeds both g3 (hval) and d3 (hval^2) accs.
// zeta1 direct from global: 16 kc-lanes x 64B contiguous runs; prefetch
// offsets are compile-time immediates. Weights in LDS interleaved 20-float
// rows (80B stride -> 2-way bank aliasing = free), 5 x b128 per k amortized
// over TM=2 rows x 2 acc sets = 40 FMAs.
__global__ __launch_bounds__(400, 4) void k_layer2(
    const float* __restrict__ A, const float* __restrict__ S,
    const float* __restrict__ mu3, const float* __restrict__ sigma3,
    const float* __restrict__ zeta1, const float* __restrict__ zeta3,
    float* __restrict__ out) {
    int b  = blockIdx.x;          // 0..511
    int g  = blockIdx.y;          // 0..3
    int mb = blockIdx.z * 50;     // mc chunk base: 0 or 50

    __shared__ float as_s[2 * HN];      // 3.2 KB  [k][2] = {A,S}
    __shared__ float wv_s[HN * 20];     // 32 KB   [k][20] = {w0-3,v0-3,w4-7,v4-7,w8,w9,v8,v9}
    __shared__ float outsh[25][ON];

    int t = threadIdx.x;

    for (int i = t; i < HN; i += 400) {
        size_t src = ((size_t)g * BN + b) * HN + i;
        as_s[2 * i]     = A[src];
        as_s[2 * i + 1] = S[src];
    }
    for (int i = t; i < HN * ON; i += 400) {
        int h = i / ON, o = i % ON;
        int wslot = (o < 4) ? o       : (o < 8) ? (4 + o) : (8 + o);   // 0-3, 8-11, 16-17
        int vslot = (o < 4) ? (4 + o) : (o < 8) ? (8 + o) : (10 + o);  // 4-7, 12-15, 18-19
        size_t src = (size_t)g * HN * ON + i;
        wv_s[h * 20 + wslot] = mu3[src];
        wv_s[h * 20 + vslot] = sp2f(sigma3[src]);
    }
    __syncthreads();

    int rg = t / 16;    // 0..24  (m = mb + rg + 25*i)
    int kc = t % 16;    // 0..15  (k = kc + 16*j)

    float accg[2][ON], accd[2][ON];
    #pragma unroll
    for (int i = 0; i < 2; ++i)
        #pragma unroll
        for (int o = 0; o < ON; ++o) { accg[i][o] = 0.0f; accd[i][o] = 0.0f; }

    const float* zp0 = zeta1 + ((size_t)(g * MCN + mb + rg)      * BN + b) * HN + kc;
    const float* zp1 = zeta1 + ((size_t)(g * MCN + mb + rg + 25) * BN + b) * HN + kc;

    float zc0 = zp0[0], zc1 = zp1[0];

    #pragma unroll 1
    for (int j = 0; j < 25; ++j) {
        float zn0 = 0.0f, zn1 = 0.0f;
        if (j < 24) { zn0 = zp0[16 * (j + 1)]; zn1 = zp1[16 * (j + 1)]; }
        int k = kc + 16 * j;
        float2 as = *(const float2*)(as_s + 2 * k);
        const float* wr = wv_s + k * 20;
        float4 w03 = *(const float4*)(wr);
        float4 v03 = *(const float4*)(wr + 4);
        float4 w47 = *(const float4*)(wr + 8);
        float4 v47 = *(const float4*)(wr + 12);
        float4 t4  = *(const float4*)(wr + 16);  // w8 w9 v8 v9

        float h0 = fmaxf(0.0f, fmaf(as.y, zc0, as.x));
        float h1 = fmaxf(0.0f, fmaf(as.y, zc1, as.x));
        float q0 = h0 * h0;
        float q1 = h1 * h1;

        accg[0][0] = fmaf(h0, w03.x, accg[0][0]);  accg[1][0] = fmaf(h1, w03.x, accg[1][0]);
        accg[0][1] = fmaf(h0, w03.y, accg[0][1]);  accg[1][1] = fmaf(h1, w03.y, accg[1][1]);
        accg[0][2] = fmaf(h0, w03.z, accg[0][2]);  accg[1][2] = fmaf(h1, w03.z, accg[1][2]);
        accg[0][3] = fmaf(h0, w03.w, accg[0][3]);  accg[1][3] = fmaf(h1, w03.w, accg[1][3]);
        accg[0][4] = fmaf(h0, w47.x, accg[0][4]);  accg[1][4] = fmaf(h1, w47.x, accg[1][4]);
        accg[0][5] = fmaf(h0, w47.y, accg[0][5]);  accg[1][5] = fmaf(h1, w47.y, accg[1][5]);
        accg[0][6] = fmaf(h0, w47.z, accg[0][6]);  accg[1][6] = fmaf(h1, w47.z, accg[1][6]);
        accg[0][7] = fmaf(h0, w47.w, accg[0][7]);  accg[1][7] = fmaf(h1, w47.w, accg[1][7]);
        accg[0][8] = fmaf(h0, t4.x,  accg[0][8]);  accg[1][8] = fmaf(h1, t4.x,  accg[1][8]);
        accg[0][9] = fmaf(h0, t4.y,  accg[0][9]);  accg[1][9] = fmaf(h1, t4.y,  accg[1][9]);

        accd[0][0] = fmaf(q0, v03.x, accd[0][0]);  accd[1][0] = fmaf(q1, v03.x, accd[1][0]);
        accd[0][1] = fmaf(q0, v03.y, accd[0][1]);  accd[1][1] = fmaf(q1, v03.y, accd[1][1]);
        accd[0][2] = fmaf(q0, v03.z, accd[0][2]);  accd[1][2] = fmaf(q1, v03.z, accd[1][2]);
        accd[0][3] = fmaf(q0, v03.w, accd[0][3]);  accd[1][3] = fmaf(q1, v03.w, accd[1][3]);
        accd[0][4] = fmaf(q0, v47.x, accd[0][4]);  accd[1][4] = fmaf(q1, v47.x, accd[1][4]);
        accd[0][5] = fmaf(q0, v47.y, accd[0][5]);  accd[1][5] = fmaf(q1, v47.y, accd[1][5]);
        accd[0][6] = fmaf(q0, v47.z, accd[0][6]);  accd[1][6] = fmaf(q1, v47.z, accd[1][6]);
        accd[0][7] = fmaf(q0, v47.w, accd[0][7]);  accd[1][7] = fmaf(q1, v47.w, accd[1][7]);
        accd[0][8] = fmaf(q0, t4.z,  accd[0][8]);  accd[1][8] = fmaf(q1, t4.z,  accd[1][8]);
        accd[0][9] = fmaf(q0, t4.w,  accd[0][9]);  accd[1][9] = fmaf(q1, t4.w,  accd[1][9]);

        zc0 = zn0; zc1 = zn1;
    }

    // reduce over the 16 kc lanes (butterfly stays inside 16-lane groups)
    #pragma unroll
    for (int i = 0; i < 2; ++i)
        #pragma unroll
        for (int o = 0; o < ON; ++o) {
            float vg = accg[i][o], vd = accd[i][o];
            vg += __shfl_xor(vg, 1);  vd += __shfl_xor(vd, 1);
            vg += __shfl_xor(vg, 2);  vd += __shfl_xor(vd, 2);
            vg += __shfl_xor(vg, 4);  vd += __shfl_xor(vd, 4);
            vg += __shfl_xor(vg, 8);  vd += __shfl_xor(vd, 8);
            accg[i][o] = vg; accd[i][o] = vd;
        }

    // epilogue: relu(g3 + sqrt(d3)*z3), softmax over 10, sum this thread's
    // 2 MC rows. All state local (no cross-half exchange). Fully unrolled.
    if (kc == 0) {
        float psum[ON];
        #pragma unroll
        for (int o = 0; o < ON; ++o) psum[o] = 0.0f;
        #pragma unroll
        for (int i = 0; i < 2; ++i) {
            int m = mb + rg + 25 * i;
            const float* z3p = zeta3 + ((size_t)(g * MCN + m) * BN + b) * ON;
            float ov[ON];
            float mx = 0.0f;
            #pragma unroll
            for (int o = 0; o < ON; ++o) {
                float v = fmaf(sqrtf(accd[i][o]), z3p[o], accg[i][o]);
                v = fmaxf(v, 0.0f);
                ov[o] = v;
                mx = fmaxf(mx, v);
            }
            float se = 0.0f;
            #pragma unroll
            for (int o = 0; o < ON; ++o) { float e = __expf(ov[o] - mx); ov[o] = e; se += e; }
            float r = 1.0f / se;
            #pragma unroll
            for (int o = 0; o < ON; ++o) psum[o] = fmaf(ov[o], r, psum[o]);
        }
        #pragma unroll
        for (int o = 0; o < ON; ++o) outsh[rg][o] = psum[o];
    }
    __syncthreads();
    if (t < ON) {
        float s = 0.0f;
        #pragma unroll
        for (int r = 0; r < 25; ++r) s += outsh[r][t];
        atomicAdd(&out[b * (GN * ON) + g * ON + t], s * (1.0f / MCN));
    }
}

extern "C" void kernel_launch(void* const* d_in, const int* in_sizes, int n_in,
                              void* d_out, int out_size, void* d_ws, size_t ws_size,
                              hipStream_t stream) {
    const float* x      = (const float*)d_in[0];
    const float* mu1    = (const float*)d_in[1];
    const float* sigma1 = (const float*)d_in[2];
    const float* mu3    = (const float*)d_in[3];
    const float* sigma3 = (const float*)d_in[4];
    const float* zeta1  = (const float*)d_in[5];
    const float* zeta3  = (const float*)d_in[6];
    // d_in[7] = num (always 3 -> G = 4, baked into GN)

    float* ws  = (float*)d_ws;
    float* xT  = ws;                       // 456*512  = 233472
    float* xxT = xT  + INN * BN;           // 233472
    float* sp1 = xxT + INN * BN;           // 4*456*400 = 729600
    float* A   = sp1 + GN * INN * HN;      // 4*512*400 = 819200
    float* S   = A   + GN * BN * HN;       // 819200
    float* out = (float*)d_out;            // 512*40

    k_zero<<<dim3((BN * GN * ON + 255) / 256), 256, 0, stream>>>(out);
    k_transpose<<<dim3(8, 8), 256, 0, stream>>>(x, xT, xxT);
    k_sp1<<<dim3((GN * INN * HN / 4 + 255) / 256), 256, 0, stream>>>(sigma1, sp1);
    k_layer1<<<dim3(32, 7, GN), 256, 0, stream>>>(xT, xxT, mu1, sp1, A, S);
    k_layer2<<<dim3(BN, GN, 2), 400, 0, stream>>>(A, S, mu3, sigma3, zeta1, zeta3, out);
}